// Round 18
// baseline (1692.240 us; speedup 1.0000x reference)
//
#include <hip/hip_runtime.h>
#include <hip/hip_bf16.h>
#include <hip/hip_fp16.h>

typedef short bf16x8 __attribute__((ext_vector_type(8)));
typedef float f32x4 __attribute__((ext_vector_type(4)));
typedef unsigned short u16x4 __attribute__((ext_vector_type(4)));
typedef unsigned int uint32;

#define MFMA_B16(a,b,c) __builtin_amdgcn_mfma_f32_16x16x32_bf16(a,b,c,0,0,0)

// ---------------- geometry ----------------
#define NS   1024
#define TLEN 128
#define DD   343
#define HH   150
#define GG   600
#define KX   352
#define XR   360    // LDS row width for x tiles (720B = 45x16B odd)
#define HR   168
#define KXP  44
#define NP   640    // gate-major: n' = gate*160 + j
#define NG2  640

// ---------------- ws layout (bytes) ----------------
#define OFF_WXP  0u
#define OFF_WHP  901120u
#define OFF_B1   1310720u
#define OFF_W2B  1315840u
#define OFF_W2I  1725440u
#define OFF_SE   3184640u
#define OFF_XG2  4413440u
#define OFF_H2O  9656320u
#define OFF_XG1  10885120ull        // bf16 [2][CS][128][640], CS adaptive

// prep section boundaries
#define PE0 450560
#define PE1 655360
#define PE2 656640
#define PE3 861440
#define PE4 1226240

__device__ __forceinline__ float rcp_fast(float x) { return __builtin_amdgcn_rcpf(x); }
__device__ __forceinline__ float sigm(float x) { return rcp_fast(1.f + __expf(-x)); }
__device__ __forceinline__ float tanh_fast(float x) { return 1.f - 2.f * rcp_fast(__expf(2.f * x) + 1.f); }

__device__ __forceinline__ void bar_lds() {
  asm volatile("s_waitcnt lgkmcnt(0)" ::: "memory");
  __builtin_amdgcn_s_barrier();
  asm volatile("" ::: "memory");
}

__device__ __forceinline__ unsigned short f2bu(float v) {
  __hip_bfloat16 b = __float2bfloat16(v);
  return __builtin_bit_cast(unsigned short, b);
}

// ---------------- prep: pack weights gate-major ----------------
__global__ __launch_bounds__(256) void prep_kernel(
    const float* __restrict__ wif1, const float* __restrict__ whf1,
    const float* __restrict__ bif1, const float* __restrict__ bhf1,
    const float* __restrict__ wib1, const float* __restrict__ whb1,
    const float* __restrict__ bib1, const float* __restrict__ bhb1,
    const float* __restrict__ wif2, const float* __restrict__ wib2,
    const float* __restrict__ whf2, const float* __restrict__ whb2,
    __hip_bfloat16* __restrict__ WXp, __hip_bfloat16* __restrict__ WHp,
    float* __restrict__ B1, __hip_bfloat16* __restrict__ W2B, float* __restrict__ W2I)
{
  int i = blockIdx.x * 256 + threadIdx.x;
  if (i < PE0) {
    int d = i / 225280; int r = i - d * 225280;
    int p = r / 5120;   int r2 = r - p * 5120;
    int n2 = r2 >> 3;   int jj = r2 & 7;
    int k = p * 8 + jj;
    int g = n2 / 160, j = n2 - g * 160;
    const float* w = d ? wib1 : wif1;
    float v = (j < HH && k < DD) ? w[(g * HH + j) * DD + k] : 0.f;
    WXp[i] = __float2bfloat16(v);
  } else if (i < PE1) {
    int ii = i - PE0;
    int d = ii / 102400; int r = ii - d * 102400;
    int p = r / 5120;    int r2 = r - p * 5120;
    int n2 = r2 >> 3;    int jj = r2 & 7;
    int k = p * 8 + jj;
    int g = n2 / 160, j = n2 - g * 160;
    const float* w = d ? whb1 : whf1;
    float v = (j < HH && k < HH) ? w[(g * HH + j) * HH + k] : 0.f;
    WHp[ii] = __float2bfloat16(v);
  } else if (i < PE2) {
    int ii = i - PE1;
    int d = ii / NP; int n2 = ii - d * NP;
    int g = n2 / 160, j = n2 - g * 160;
    float v = 0.f;
    if (j < HH) {
      int n = g * HH + j;
      v = d ? (bib1[n] + bhb1[n]) : (bif1[n] + bhf1[n]);
    }
    B1[ii] = v;
  } else if (i < PE3) {
    int ii = i - PE2;
    int d = ii / 102400; int r = ii - d * 102400;
    int n2 = r / 160;    int k = r - n2 * 160;
    int g = n2 / 160, j = n2 - g * 160;
    const float* w = d ? whb2 : whf2;
    float v = (j < HH && k < HH) ? w[(g * HH + j) * HH + k] : 0.f;
    W2B[ii] = __float2bfloat16(v);
  } else if (i < PE4) {
    int ii = i - PE3;
    int d = ii / 182400; int r = ii - d * 182400;
    int k = r / 608;     int n = r - k * 608;
    const float* w = d ? wib2 : wif2;
    float v = (n < GG) ? w[n * 300 + k] : 0.f;
    W2I[ii] = v;
  }
}

// ---------------- layer-1 input GEMM (chunked, M=64): XG1 = x @ WXp^T + B1 ----------------
// Block = (sentence, m-half). A (64x352 bf16, 45KB) staged once from f32 x;
// reused by 2 dirs x 2 n-halves. 45KB LDS -> 2-3 blocks/CU: one block's
// staging overlaps another's MFMA compute (round-17 had 90KB -> 1 block/CU,
// stage fully serialized with compute). Grid = 2*CS.
#define GA_SMEM (64u * 720u)   // 46080

__global__ __launch_bounds__(512) void xg1_gemm(
    const float* __restrict__ x, const __hip_bfloat16* __restrict__ WXp,
    const float* __restrict__ B1, __hip_bfloat16* __restrict__ XG1,
    int sBase, int CS)
{
  extern __shared__ char smem[];
  __hip_bfloat16* xsA = (__hip_bfloat16*)smem;

  const int bid = blockIdx.x;
  const int mh = bid & 1;
  const int mtl = bid >> 1;            // chunk-local sentence
  const int sg = sBase + mtl;

  const int tid = threadIdx.x;
  const int lane = tid & 63;
  const int wv = tid >> 6;             // 0..7
  const int wr = wv >> 2;              // 0..1 (m 32-half)
  const int wc = wv & 3;               // 0..3 (n-slice of 80)
  const int c16 = lane & 15;
  const int kgrp = lane >> 4;

  // stage A: 64 rows, f32 -> bf16, rows 720B (odd 16B stride)
  for (int g = tid; g < 5632; g += 512) {
    int row = g / 88;
    int c4 = (g - row * 88) * 4;
    const float* src = x + (((size_t)sg * TLEN + mh * 64 + row)) * DD + c4;
    float v0 = 0.f, v1 = 0.f, v2 = 0.f, v3 = 0.f;
    if (c4 + 3 < DD) { v0 = src[0]; v1 = src[1]; v2 = src[2]; v3 = src[3]; }
    else {
      if (c4 < DD)     v0 = src[0];
      if (c4 + 1 < DD) v1 = src[1];
      if (c4 + 2 < DD) v2 = src[2];
    }
    u16x4 o;
    o.x = f2bu(v0); o.y = f2bu(v1); o.z = f2bu(v2); o.w = f2bu(v3);
    *(u16x4*)(smem + row * 720 + c4 * 2) = o;
  }
  bar_lds();

  for (int dir = 0; dir < 2; ++dir) {
    const __hip_bfloat16* WXd = WXp + (size_t)dir * KXP * NP * 8;
    __hip_bfloat16* outd = XG1 + ((size_t)dir * CS + mtl) * TLEN * NG2;

    #pragma unroll
    for (int nh = 0; nh < 2; ++nh) {
      const int nbase = nh * 320 + wc * 80;
      f32x4 acc[2][5];
      #pragma unroll
      for (int mi = 0; mi < 2; ++mi)
        #pragma unroll
        for (int nf = 0; nf < 5; ++nf) acc[mi][nf] = (f32x4){0.f, 0.f, 0.f, 0.f};

      for (int kk = 0; kk < 11; ++kk) {
        bf16x8 a[2], b[5];
        #pragma unroll
        for (int mi = 0; mi < 2; ++mi)
          a[mi] = *reinterpret_cast<const bf16x8*>(
              xsA + (wr * 32 + mi * 16 + c16) * XR + kk * 32 + kgrp * 8);
        #pragma unroll
        for (int nf = 0; nf < 5; ++nf)
          b[nf] = *reinterpret_cast<const bf16x8*>(
              WXd + ((size_t)(kk * 4 + kgrp) * NP + nbase + nf * 16 + c16) * 8);
        #pragma unroll
        for (int mi = 0; mi < 2; ++mi)
          #pragma unroll
          for (int nf = 0; nf < 5; ++nf)
            acc[mi][nf] = MFMA_B16(a[mi], b[nf], acc[mi][nf]);
      }

      float bias[5];
      #pragma unroll
      for (int nf = 0; nf < 5; ++nf)
        bias[nf] = B1[dir * NP + nbase + nf * 16 + c16];

      #pragma unroll
      for (int mi = 0; mi < 2; ++mi)
        #pragma unroll
        for (int r = 0; r < 4; ++r) {
          int t = mh * 64 + wr * 32 + mi * 16 + kgrp * 4 + r;
          __hip_bfloat16* row = outd + (size_t)t * NG2;
          #pragma unroll
          for (int nf = 0; nf < 5; ++nf)
            row[nbase + nf * 16 + c16] = __float2bfloat16(acc[mi][nf][r] + bias[nf]);
        }
    }
  }
}

// ---------------- layer-1 recurrence (reads bf16 XG1 chunk) ----------------
__global__ __launch_bounds__(640) void lstm1_rec(
    const __hip_bfloat16* __restrict__ XG1, const __hip_bfloat16* __restrict__ WHp,
    float* __restrict__ SE, int sBase, int CS)
{
  __shared__ __hip_bfloat16 hs[16 * HR];

  const int tid = threadIdx.x;
  const int lane = tid & 63;
  const int wv = tid >> 6;
  const int dir = blockIdx.x & 1;
  const int grp = blockIdx.x >> 1;
  const int cls0 = grp * 8;
  const int s0g = sBase + cls0;
  const int c16 = lane & 15;
  const int kgrp = lane >> 4;
  const int j = wv * 16 + c16;

  for (int e = tid; e < 16 * HR; e += 640) hs[e] = __float2bfloat16(0.f);

  const __hip_bfloat16* WHd = WHp + (size_t)dir * 20 * NP * 8;
  bf16x8 whr[5][4];
  #pragma unroll
  for (int kh = 0; kh < 5; ++kh)
    #pragma unroll
    for (int g4 = 0; g4 < 4; ++g4) {
      whr[kh][g4] = *reinterpret_cast<const bf16x8*>(
          WHd + ((size_t)(kh * 4 + kgrp) * NP + g4 * 160 + j) * 8);
      asm volatile("" : "+v"(whr[kh][g4]));
    }

  float creg[4] = {0.f, 0.f, 0.f, 0.f};
  float mxr[4] = {-3e38f, -3e38f, -3e38f, -3e38f};

  const __hip_bfloat16* xgd = XG1 + (size_t)dir * CS * TLEN * NG2;
  const int sentb = cls0 + (kgrp & 1) * 4;
  const int par = kgrp >> 1;

  float xq[16], xqN[16];
  #pragma unroll
  for (int g4 = 0; g4 < 4; ++g4)
    #pragma unroll
    for (int r = 0; r < 4; ++r) {
      int tt = dir ? (127 - par) : par;
      xq[g4 * 4 + r] = __bfloat162float(
          xgd[((size_t)(sentb + r) * TLEN + tt) * NG2 + g4 * 160 + j]);
    }
  __syncthreads();

  for (int p = 0; p < 64; ++p) {
    f32x4 acc[4];
    #pragma unroll
    for (int g4 = 0; g4 < 4; ++g4) {
      acc[g4][0] = xq[g4 * 4 + 0]; acc[g4][1] = xq[g4 * 4 + 1];
      acc[g4][2] = xq[g4 * 4 + 2]; acc[g4][3] = xq[g4 * 4 + 3];
    }
    if (p < 63) {
      #pragma unroll
      for (int g4 = 0; g4 < 4; ++g4)
        #pragma unroll
        for (int r = 0; r < 4; ++r) {
          int tl = 2 * (p + 1) + par;
          int tt = dir ? (127 - tl) : tl;
          xqN[g4 * 4 + r] = __bfloat162float(
              xgd[((size_t)(sentb + r) * TLEN + tt) * NG2 + g4 * 160 + j]);
        }
    }
    #pragma unroll
    for (int kh = 0; kh < 5; ++kh) {
      bf16x8 ah = *reinterpret_cast<const bf16x8*>(hs + c16 * HR + kh * 32 + kgrp * 8);
      #pragma unroll
      for (int g4 = 0; g4 < 4; ++g4)
        acc[g4] = MFMA_B16(ah, whr[kh][g4], acc[g4]);
    }
    {
      const bool act = (kgrp < 2);
      #pragma unroll
      for (int r = 0; r < 4; ++r) {
        float iv = sigm(acc[0][r]);
        float fv = sigm(acc[1][r]);
        float gv = tanh_fast(acc[2][r]);
        float ov = sigm(acc[3][r]);
        float cin = __shfl_xor(creg[r], 32);
        float cn = fv * cin + iv * gv;
        float h = ov * tanh_fast(cn);
        creg[r] = act ? cn : creg[r];
        mxr[r] = act ? fmaxf(mxr[r], h) : mxr[r];
        if (act) hs[(8 + kgrp * 4 + r) * HR + j] = __float2bfloat16(h);
      }
    }
    bar_lds();
    #pragma unroll
    for (int kh = 0; kh < 5; ++kh) {
      bf16x8 ah = *reinterpret_cast<const bf16x8*>(hs + c16 * HR + kh * 32 + kgrp * 8);
      #pragma unroll
      for (int g4 = 0; g4 < 4; ++g4)
        acc[g4] = MFMA_B16(ah, whr[kh][g4], acc[g4]);
    }
    {
      const bool act = (kgrp >= 2);
      #pragma unroll
      for (int r = 0; r < 4; ++r) {
        float iv = sigm(acc[0][r]);
        float fv = sigm(acc[1][r]);
        float gv = tanh_fast(acc[2][r]);
        float ov = sigm(acc[3][r]);
        float cin = __shfl_xor(creg[r], 32);
        float cn = fv * cin + iv * gv;
        float h = ov * tanh_fast(cn);
        creg[r] = act ? cn : creg[r];
        mxr[r] = act ? fmaxf(mxr[r], h) : mxr[r];
        if (act) {
          int s = (kgrp - 2) * 4 + r;
          hs[s * HR + j] = __float2bfloat16(h);
          hs[(8 + s) * HR + j] = __float2bfloat16(0.f);
        }
      }
    }
    bar_lds();
    #pragma unroll
    for (int q = 0; q < 16; ++q) xq[q] = xqN[q];
  }

  #pragma unroll
  for (int r = 0; r < 4; ++r) {
    float m = fmaxf(mxr[r], __shfl_xor(mxr[r], 32));
    if (kgrp < 2 && j < HH)
      SE[(size_t)(s0g + kgrp * 4 + r) * 300 + dir * HH + j] = m;
  }
}

// ---------------- layer-2 input projection ----------------
__global__ __launch_bounds__(256, 1) void xg2_kernel(
    const float* __restrict__ SE, const float* __restrict__ W2I,
    const float* __restrict__ bif2, const float* __restrict__ bhf2,
    const float* __restrict__ bib2, const float* __restrict__ bhb2,
    float* __restrict__ XG2)
{
  __shared__ float se[32 * 304];
  const int d = blockIdx.x >> 5, st = blockIdx.x & 31, sb = st * 32;
  const int tid = threadIdx.x;
  for (int e = tid; e < 32 * 300; e += 256) {
    int si = e / 300, k = e - si * 300;
    se[si * 304 + k] = SE[(size_t)(sb + si) * 300 + k];
  }
  __syncthreads();
  for (int pass = 0; pass < 3; ++pass) {
    int n = pass * 256 + tid;
    if (n < GG) {
      int n2 = (n / 150) * 160 + (n % 150);
      float bias = d ? (bib2[n] + bhb2[n]) : (bif2[n] + bhf2[n]);
      float acc[32];
      #pragma unroll
      for (int si = 0; si < 32; ++si) acc[si] = bias;
      const float* wcol = W2I + (size_t)d * 300 * 608 + n;
      for (int k = 0; k < 300; ++k) {
        float wvv = wcol[(size_t)k * 608];
        #pragma unroll
        for (int si = 0; si < 32; ++si) acc[si] += wvv * se[si * 304 + k];
      }
      #pragma unroll
      for (int si = 0; si < 32; ++si)
        XG2[((size_t)d * NS + sb + si) * NG2 + n2] = acc[si];
    }
  }
  for (int e = tid; e < 32 * 40; e += 256) {
    int si = e / 40, q = e - si * 40;
    int g = q / 10, jp = 150 + (q - g * 10);
    XG2[((size_t)d * NS + sb + si) * NG2 + g * 160 + jp] = 0.f;
  }
}

// ---------------- layer-2 recurrence: depth-1 MFMA chains ----------------
__global__ __launch_bounds__(640) void lstm2_kernel(
    const __hip_bfloat16* __restrict__ W2B, const float* __restrict__ XG2,
    float* __restrict__ H2O)
{
  const int dir = blockIdx.x;
  const int tid = threadIdx.x;
  const int lane = tid & 63;
  const int wv = tid >> 6;
  const int c16 = lane & 15;
  const int kg = lane >> 4;
  const int j = wv * 16 + c16;
  __shared__ __align__(16) __hip_bfloat16 hbuf[2][160];

  const f32x4 ZERO4 = {0.f, 0.f, 0.f, 0.f};

  const __hip_bfloat16* Wd = W2B + (size_t)dir * NP * 160;
  bf16x8 wf[5][4];
  #pragma unroll
  for (int kt = 0; kt < 5; ++kt)
    #pragma unroll
    for (int g4 = 0; g4 < 4; ++g4) {
      wf[kt][g4] = *reinterpret_cast<const bf16x8*>(
          Wd + (size_t)(g4 * 160 + j) * 160 + kt * 32 + kg * 8);
      asm volatile("" : "+v"(wf[kt][g4]));
    }

  if (tid < 160) hbuf[0][tid] = __float2bfloat16(0.f);
  __syncthreads();

  float creg = 0.f;
  const float* xg = XG2 + (size_t)dir * NS * NG2;

  float xqC[8], xqN[8];
  #pragma unroll
  for (int q = 0; q < 2; ++q)
    #pragma unroll
    for (int g4 = 0; g4 < 4; ++g4) {
      int ss2 = dir ? (1023 - q) : q;
      xqC[q * 4 + g4] = xg[(size_t)ss2 * NG2 + g4 * 160 + j];
    }

  for (int grp = 0; grp < 512; ++grp) {
    #pragma unroll
    for (int q = 0; q < 2; ++q)
      #pragma unroll
      for (int g4 = 0; g4 < 4; ++g4) {
        int sl = grp * 2 + 2 + q;
        if (sl < 1024) {
          int ss2 = dir ? (1023 - sl) : sl;
          xqN[q * 4 + g4] = xg[(size_t)ss2 * NG2 + g4 * 160 + j];
        } else {
          xqN[q * 4 + g4] = 0.f;
        }
      }
    #pragma unroll
    for (int q = 0; q < 2; ++q) {
      const int step = grp * 2 + q;
      const int ss = dir ? (1023 - step) : step;
      bf16x8 hf[5];
      #pragma unroll
      for (int kt = 0; kt < 5; ++kt)
        hf[kt] = *reinterpret_cast<const bf16x8*>(&hbuf[q][kt * 32 + kg * 8]);
      // depth-1: 20 independent MFMAs, reduce on VALU (serial chain = 1 MFMA
      // latency instead of 3 at the ~800MHz this near-idle-GPU phase runs at)
      float y[4];
      #pragma unroll
      for (int g4 = 0; g4 < 4; ++g4) {
        f32x4 c0 = MFMA_B16(hf[0], wf[0][g4], ZERO4);
        f32x4 c1 = MFMA_B16(hf[1], wf[1][g4], ZERO4);
        f32x4 c2 = MFMA_B16(hf[2], wf[2][g4], ZERO4);
        f32x4 c3 = MFMA_B16(hf[3], wf[3][g4], ZERO4);
        f32x4 c4 = MFMA_B16(hf[4], wf[4][g4], ZERO4);
        y[g4] = ((c0[0] + c1[0]) + (c2[0] + c3[0])) + c4[0];
      }
      float iv = sigm(y[0] + xqC[q * 4 + 0]);
      float fv = sigm(y[1] + xqC[q * 4 + 1]);
      float gv = tanh_fast(y[2] + xqC[q * 4 + 2]);
      float ov = sigm(y[3] + xqC[q * 4 + 3]);
      creg = fv * creg + iv * gv;
      float nh = ov * tanh_fast(creg);
      if (kg == 0) {
        hbuf[q ^ 1][j] = __float2bfloat16(nh);
        if (j < HH) H2O[(size_t)ss * 300 + dir * HH + j] = nh;
      }
      bar_lds();
    }
    #pragma unroll
    for (int q = 0; q < 8; ++q) xqC[q] = xqN[q];
  }
}

// ---------------- head ----------------
__global__ __launch_bounds__(256, 1) void head_kernel(
    const float* __restrict__ H2O, const float* __restrict__ w_out,
    const float* __restrict__ b_out, float* __restrict__ out)
{
  int s = blockIdx.x * 256 + threadIdx.x;
  if (s >= NS) return;
  float acc[7];
  #pragma unroll
  for (int c = 0; c < 7; ++c) acc[c] = b_out[c];
  const float* hrow = H2O + (size_t)s * 300;
  for (int k = 0; k < 300; ++k) {
    float hv = hrow[k];
    #pragma unroll
    for (int c = 0; c < 7; ++c) acc[c] += hv * w_out[c * 300 + k];
  }
  float m = acc[0];
  #pragma unroll
  for (int c = 1; c < 7; ++c) m = fmaxf(m, acc[c]);
  float sum = 0.f;
  #pragma unroll
  for (int c = 0; c < 7; ++c) sum += __expf(acc[c] - m);
  float lse = m + __logf(sum);
  #pragma unroll
  for (int c = 0; c < 7; ++c) out[s * 7 + c] = acc[c] - lse;
}

extern "C" void kernel_launch(void* const* d_in, const int* in_sizes, int n_in,
                              void* d_out, int out_size, void* d_ws, size_t ws_size,
                              hipStream_t stream) {
  const float* x      = (const float*)d_in[0];
  const float* wif1   = (const float*)d_in[1];
  const float* whf1   = (const float*)d_in[2];
  const float* bif1   = (const float*)d_in[3];
  const float* bhf1   = (const float*)d_in[4];
  const float* wib1   = (const float*)d_in[5];
  const float* whb1   = (const float*)d_in[6];
  const float* bib1   = (const float*)d_in[7];
  const float* bhb1   = (const float*)d_in[8];
  const float* wif2   = (const float*)d_in[9];
  const float* whf2   = (const float*)d_in[10];
  const float* bif2   = (const float*)d_in[11];
  const float* bhf2   = (const float*)d_in[12];
  const float* wib2   = (const float*)d_in[13];
  const float* whb2   = (const float*)d_in[14];
  const float* bib2   = (const float*)d_in[15];
  const float* bhb2   = (const float*)d_in[16];
  const float* w_out  = (const float*)d_in[17];
  const float* b_out  = (const float*)d_in[18];

  char* ws = (char*)d_ws;
  __hip_bfloat16* WXp = (__hip_bfloat16*)(ws + OFF_WXP);
  __hip_bfloat16* WHp = (__hip_bfloat16*)(ws + OFF_WHP);
  float*    B1  = (float*)(ws + OFF_B1);
  __hip_bfloat16* W2B = (__hip_bfloat16*)(ws + OFF_W2B);
  float*    W2I = (float*)(ws + OFF_W2I);
  float*    SE  = (float*)(ws + OFF_SE);
  float*    XG2 = (float*)(ws + OFF_XG2);
  float*    H2O = (float*)(ws + OFF_H2O);
  __hip_bfloat16* XG1 = (__hip_bfloat16*)(ws + OFF_XG1);

  // adaptive chunk: XG1 chunk bytes = CS * 327680 (bf16 [2][CS][128][640]).
  int CS = 128;
  if (ws_size > OFF_XG1) {
    size_t avail = ws_size - OFF_XG1;
    CS = 1024;
    while (CS > 128 && (size_t)CS * 327680ull > avail) CS >>= 1;
  }

  prep_kernel<<<(PE4 + 255) / 256, 256, 0, stream>>>(
      wif1, whf1, bif1, bhf1, wib1, whb1, bib1, bhb1,
      wif2, wib2, whf2, whb2, WXp, WHp, B1, W2B, W2I);

  (void)hipFuncSetAttribute((const void*)xg1_gemm,
                            hipFuncAttributeMaxDynamicSharedMemorySize, GA_SMEM);
  for (int sBase = 0; sBase < NS; sBase += CS) {
    xg1_gemm<<<2 * CS, 512, GA_SMEM, stream>>>(x, WXp, B1, XG1, sBase, CS);
    lstm1_rec<<<CS / 4, 640, 0, stream>>>(XG1, WHp, SE, sBase, CS);
  }

  xg2_kernel<<<64, 256, 0, stream>>>(SE, W2I, bif2, bhf2, bib2, bhb2, XG2);

  lstm2_kernel<<<2, 640, 0, stream>>>(W2B, XG2, H2O);

  head_kernel<<<4, 256, 0, stream>>>(H2O, w_out, b_out, (float*)d_out);
}

// Round 19
// 1349.474 us; speedup vs baseline: 1.2540x; 1.2540x over previous
//
#include <hip/hip_runtime.h>
#include <hip/hip_bf16.h>
#include <hip/hip_fp16.h>

typedef short bf16x8 __attribute__((ext_vector_type(8)));
typedef float f32x4 __attribute__((ext_vector_type(4)));
typedef unsigned short u16x4 __attribute__((ext_vector_type(4)));
typedef unsigned int uint32;

#define MFMA_B16(a,b,c) __builtin_amdgcn_mfma_f32_16x16x32_bf16(a,b,c,0,0,0)

// ---------------- geometry ----------------
#define NS   1024
#define TLEN 128
#define DD   343
#define HH   150
#define GG   600
#define KX   352
#define XR   360    // LDS row width for x tiles (720B = 45x16B odd)
#define HR   168
#define KXP  44
#define NP   640    // gate-major: n' = gate*160 + j
#define NG2  640

// ---------------- ws layout (bytes) ----------------
#define OFF_WXP  0u
#define OFF_WHP  901120u
#define OFF_B1   1310720u
#define OFF_W2B  1315840u
#define OFF_W2I  1725440u
#define OFF_SE   3184640u
#define OFF_XG2  4413440u
#define OFF_H2O  9656320u
#define OFF_XG1  10885120ull        // bf16 [2][CS][128][640], CS adaptive

// prep section boundaries
#define PE0 450560
#define PE1 655360
#define PE2 656640
#define PE3 861440
#define PE4 1226240

__device__ __forceinline__ float rcp_fast(float x) { return __builtin_amdgcn_rcpf(x); }
__device__ __forceinline__ float sigm(float x) { return rcp_fast(1.f + __expf(-x)); }
__device__ __forceinline__ float tanh_fast(float x) { return 1.f - 2.f * rcp_fast(__expf(2.f * x) + 1.f); }

__device__ __forceinline__ void bar_lds() {
  asm volatile("s_waitcnt lgkmcnt(0)" ::: "memory");
  __builtin_amdgcn_s_barrier();
  asm volatile("" ::: "memory");
}

__device__ __forceinline__ unsigned short f2bu(float v) {
  __hip_bfloat16 b = __float2bfloat16(v);
  return __builtin_bit_cast(unsigned short, b);
}

// ---------------- prep: pack weights gate-major ----------------
__global__ __launch_bounds__(256) void prep_kernel(
    const float* __restrict__ wif1, const float* __restrict__ whf1,
    const float* __restrict__ bif1, const float* __restrict__ bhf1,
    const float* __restrict__ wib1, const float* __restrict__ whb1,
    const float* __restrict__ bib1, const float* __restrict__ bhb1,
    const float* __restrict__ wif2, const float* __restrict__ wib2,
    const float* __restrict__ whf2, const float* __restrict__ whb2,
    __hip_bfloat16* __restrict__ WXp, __hip_bfloat16* __restrict__ WHp,
    float* __restrict__ B1, __hip_bfloat16* __restrict__ W2B, float* __restrict__ W2I)
{
  int i = blockIdx.x * 256 + threadIdx.x;
  if (i < PE0) {
    int d = i / 225280; int r = i - d * 225280;
    int p = r / 5120;   int r2 = r - p * 5120;
    int n2 = r2 >> 3;   int jj = r2 & 7;
    int k = p * 8 + jj;
    int g = n2 / 160, j = n2 - g * 160;
    const float* w = d ? wib1 : wif1;
    float v = (j < HH && k < DD) ? w[(g * HH + j) * DD + k] : 0.f;
    WXp[i] = __float2bfloat16(v);
  } else if (i < PE1) {
    int ii = i - PE0;
    int d = ii / 102400; int r = ii - d * 102400;
    int p = r / 5120;    int r2 = r - p * 5120;
    int n2 = r2 >> 3;    int jj = r2 & 7;
    int k = p * 8 + jj;
    int g = n2 / 160, j = n2 - g * 160;
    const float* w = d ? whb1 : whf1;
    float v = (j < HH && k < HH) ? w[(g * HH + j) * HH + k] : 0.f;
    WHp[ii] = __float2bfloat16(v);
  } else if (i < PE2) {
    int ii = i - PE1;
    int d = ii / NP; int n2 = ii - d * NP;
    int g = n2 / 160, j = n2 - g * 160;
    float v = 0.f;
    if (j < HH) {
      int n = g * HH + j;
      v = d ? (bib1[n] + bhb1[n]) : (bif1[n] + bhf1[n]);
    }
    B1[ii] = v;
  } else if (i < PE3) {
    int ii = i - PE2;
    int d = ii / 102400; int r = ii - d * 102400;
    int n2 = r / 160;    int k = r - n2 * 160;
    int g = n2 / 160, j = n2 - g * 160;
    const float* w = d ? whb2 : whf2;
    float v = (j < HH && k < HH) ? w[(g * HH + j) * HH + k] : 0.f;
    W2B[ii] = __float2bfloat16(v);
  } else if (i < PE4) {
    int ii = i - PE3;
    int d = ii / 182400; int r = ii - d * 182400;
    int k = r / 608;     int n = r - k * 608;
    const float* w = d ? wib2 : wif2;
    float v = (n < GG) ? w[n * 300 + k] : 0.f;
    W2I[ii] = v;
  }
}

// ---------------- layer-1 input GEMM (chunked): XG1 = x @ WXp^T + B1 (bf16 out) ----------------
// One block = one sentence. A (128x352 bf16, 90KB) staged ONCE directly from
// f32 x (reg-load -> cvt -> ds_write; x read exactly once); reused by 2 dirs x
// 2 n-halves. B (450KB/dir) stays L2-hot. Grid = CS.
#define GA_SMEM (128u * 720u)   // 92160

__global__ __launch_bounds__(512) void xg1_gemm(
    const float* __restrict__ x, const __hip_bfloat16* __restrict__ WXp,
    const float* __restrict__ B1, __hip_bfloat16* __restrict__ XG1,
    int sBase, int CS)
{
  extern __shared__ char smem[];
  __hip_bfloat16* xsA = (__hip_bfloat16*)smem;

  const int mtl = blockIdx.x;          // chunk-local sentence
  const int sg = sBase + mtl;

  const int tid = threadIdx.x;
  const int lane = tid & 63;
  const int wv = tid >> 6;             // 0..7
  const int wr = wv >> 2;              // 0..1 (m-half of 64)
  const int wc = wv & 3;               // 0..3 (n-slice of 80)
  const int c16 = lane & 15;
  const int kgrp = lane >> 4;

  // stage A: f32 -> bf16, rows 720B (odd 16B stride)
  for (int g = tid; g < 11264; g += 512) {
    int row = g / 88;
    int c4 = (g - row * 88) * 4;
    const float* src = x + ((size_t)sg * TLEN + row) * DD + c4;
    float v0 = 0.f, v1 = 0.f, v2 = 0.f, v3 = 0.f;
    if (c4 + 3 < DD) { v0 = src[0]; v1 = src[1]; v2 = src[2]; v3 = src[3]; }
    else {
      if (c4 < DD)     v0 = src[0];
      if (c4 + 1 < DD) v1 = src[1];
      if (c4 + 2 < DD) v2 = src[2];
    }
    u16x4 o;
    o.x = f2bu(v0); o.y = f2bu(v1); o.z = f2bu(v2); o.w = f2bu(v3);
    *(u16x4*)(smem + row * 720 + c4 * 2) = o;
  }
  bar_lds();

  for (int dir = 0; dir < 2; ++dir) {
    const __hip_bfloat16* WXd = WXp + (size_t)dir * KXP * NP * 8;
    __hip_bfloat16* outd = XG1 + ((size_t)dir * CS + mtl) * TLEN * NG2;

    #pragma unroll
    for (int nh = 0; nh < 2; ++nh) {
      const int nbase = nh * 320 + wc * 80;
      f32x4 acc[4][5];
      #pragma unroll
      for (int mi = 0; mi < 4; ++mi)
        #pragma unroll
        for (int nf = 0; nf < 5; ++nf) acc[mi][nf] = (f32x4){0.f, 0.f, 0.f, 0.f};

      for (int kk = 0; kk < 11; ++kk) {
        bf16x8 a[4], b[5];
        #pragma unroll
        for (int mi = 0; mi < 4; ++mi)
          a[mi] = *reinterpret_cast<const bf16x8*>(
              xsA + (wr * 64 + mi * 16 + c16) * XR + kk * 32 + kgrp * 8);
        #pragma unroll
        for (int nf = 0; nf < 5; ++nf)
          b[nf] = *reinterpret_cast<const bf16x8*>(
              WXd + ((size_t)(kk * 4 + kgrp) * NP + nbase + nf * 16 + c16) * 8);
        #pragma unroll
        for (int mi = 0; mi < 4; ++mi)
          #pragma unroll
          for (int nf = 0; nf < 5; ++nf)
            acc[mi][nf] = MFMA_B16(a[mi], b[nf], acc[mi][nf]);
      }

      float bias[5];
      #pragma unroll
      for (int nf = 0; nf < 5; ++nf)
        bias[nf] = B1[dir * NP + nbase + nf * 16 + c16];

      #pragma unroll
      for (int mi = 0; mi < 4; ++mi)
        #pragma unroll
        for (int r = 0; r < 4; ++r) {
          int t = wr * 64 + mi * 16 + kgrp * 4 + r;
          __hip_bfloat16* row = outd + (size_t)t * NG2;
          #pragma unroll
          for (int nf = 0; nf < 5; ++nf)
            row[nbase + nf * 16 + c16] = __float2bfloat16(acc[mi][nf][r] + bias[nf]);
        }
    }
  }
}

// ---------------- layer-1 recurrence (reads bf16 XG1 chunk) ----------------
__global__ __launch_bounds__(640) void lstm1_rec(
    const __hip_bfloat16* __restrict__ XG1, const __hip_bfloat16* __restrict__ WHp,
    float* __restrict__ SE, int sBase, int CS)
{
  __shared__ __hip_bfloat16 hs[16 * HR];

  const int tid = threadIdx.x;
  const int lane = tid & 63;
  const int wv = tid >> 6;
  const int dir = blockIdx.x & 1;
  const int grp = blockIdx.x >> 1;
  const int cls0 = grp * 8;
  const int s0g = sBase + cls0;
  const int c16 = lane & 15;
  const int kgrp = lane >> 4;
  const int j = wv * 16 + c16;

  for (int e = tid; e < 16 * HR; e += 640) hs[e] = __float2bfloat16(0.f);

  const __hip_bfloat16* WHd = WHp + (size_t)dir * 20 * NP * 8;
  bf16x8 whr[5][4];
  #pragma unroll
  for (int kh = 0; kh < 5; ++kh)
    #pragma unroll
    for (int g4 = 0; g4 < 4; ++g4) {
      whr[kh][g4] = *reinterpret_cast<const bf16x8*>(
          WHd + ((size_t)(kh * 4 + kgrp) * NP + g4 * 160 + j) * 8);
      asm volatile("" : "+v"(whr[kh][g4]));
    }

  float creg[4] = {0.f, 0.f, 0.f, 0.f};
  float mxr[4] = {-3e38f, -3e38f, -3e38f, -3e38f};

  const __hip_bfloat16* xgd = XG1 + (size_t)dir * CS * TLEN * NG2;
  const int sentb = cls0 + (kgrp & 1) * 4;
  const int par = kgrp >> 1;

  float xq[16], xqN[16];
  #pragma unroll
  for (int g4 = 0; g4 < 4; ++g4)
    #pragma unroll
    for (int r = 0; r < 4; ++r) {
      int tt = dir ? (127 - par) : par;
      xq[g4 * 4 + r] = __bfloat162float(
          xgd[((size_t)(sentb + r) * TLEN + tt) * NG2 + g4 * 160 + j]);
    }
  __syncthreads();

  for (int p = 0; p < 64; ++p) {
    f32x4 acc[4];
    #pragma unroll
    for (int g4 = 0; g4 < 4; ++g4) {
      acc[g4][0] = xq[g4 * 4 + 0]; acc[g4][1] = xq[g4 * 4 + 1];
      acc[g4][2] = xq[g4 * 4 + 2]; acc[g4][3] = xq[g4 * 4 + 3];
    }
    if (p < 63) {
      #pragma unroll
      for (int g4 = 0; g4 < 4; ++g4)
        #pragma unroll
        for (int r = 0; r < 4; ++r) {
          int tl = 2 * (p + 1) + par;
          int tt = dir ? (127 - tl) : tl;
          xqN[g4 * 4 + r] = __bfloat162float(
              xgd[((size_t)(sentb + r) * TLEN + tt) * NG2 + g4 * 160 + j]);
        }
    }
    #pragma unroll
    for (int kh = 0; kh < 5; ++kh) {
      bf16x8 ah = *reinterpret_cast<const bf16x8*>(hs + c16 * HR + kh * 32 + kgrp * 8);
      #pragma unroll
      for (int g4 = 0; g4 < 4; ++g4)
        acc[g4] = MFMA_B16(ah, whr[kh][g4], acc[g4]);
    }
    {
      const bool act = (kgrp < 2);
      #pragma unroll
      for (int r = 0; r < 4; ++r) {
        float iv = sigm(acc[0][r]);
        float fv = sigm(acc[1][r]);
        float gv = tanh_fast(acc[2][r]);
        float ov = sigm(acc[3][r]);
        float cin = __shfl_xor(creg[r], 32);
        float cn = fv * cin + iv * gv;
        float h = ov * tanh_fast(cn);
        creg[r] = act ? cn : creg[r];
        mxr[r] = act ? fmaxf(mxr[r], h) : mxr[r];
        if (act) hs[(8 + kgrp * 4 + r) * HR + j] = __float2bfloat16(h);
      }
    }
    bar_lds();
    #pragma unroll
    for (int kh = 0; kh < 5; ++kh) {
      bf16x8 ah = *reinterpret_cast<const bf16x8*>(hs + c16 * HR + kh * 32 + kgrp * 8);
      #pragma unroll
      for (int g4 = 0; g4 < 4; ++g4)
        acc[g4] = MFMA_B16(ah, whr[kh][g4], acc[g4]);
    }
    {
      const bool act = (kgrp >= 2);
      #pragma unroll
      for (int r = 0; r < 4; ++r) {
        float iv = sigm(acc[0][r]);
        float fv = sigm(acc[1][r]);
        float gv = tanh_fast(acc[2][r]);
        float ov = sigm(acc[3][r]);
        float cin = __shfl_xor(creg[r], 32);
        float cn = fv * cin + iv * gv;
        float h = ov * tanh_fast(cn);
        creg[r] = act ? cn : creg[r];
        mxr[r] = act ? fmaxf(mxr[r], h) : mxr[r];
        if (act) {
          int s = (kgrp - 2) * 4 + r;
          hs[s * HR + j] = __float2bfloat16(h);
          hs[(8 + s) * HR + j] = __float2bfloat16(0.f);
        }
      }
    }
    bar_lds();
    #pragma unroll
    for (int q = 0; q < 16; ++q) xq[q] = xqN[q];
  }

  #pragma unroll
  for (int r = 0; r < 4; ++r) {
    float m = fmaxf(mxr[r], __shfl_xor(mxr[r], 32));
    if (kgrp < 2 && j < HH)
      SE[(size_t)(s0g + kgrp * 4 + r) * 300 + dir * HH + j] = m;
  }
}

// ---------------- layer-2 input projection ----------------
__global__ __launch_bounds__(256, 1) void xg2_kernel(
    const float* __restrict__ SE, const float* __restrict__ W2I,
    const float* __restrict__ bif2, const float* __restrict__ bhf2,
    const float* __restrict__ bib2, const float* __restrict__ bhb2,
    float* __restrict__ XG2)
{
  __shared__ float se[32 * 304];
  const int d = blockIdx.x >> 5, st = blockIdx.x & 31, sb = st * 32;
  const int tid = threadIdx.x;
  for (int e = tid; e < 32 * 300; e += 256) {
    int si = e / 300, k = e - si * 300;
    se[si * 304 + k] = SE[(size_t)(sb + si) * 300 + k];
  }
  __syncthreads();
  for (int pass = 0; pass < 3; ++pass) {
    int n = pass * 256 + tid;
    if (n < GG) {
      int n2 = (n / 150) * 160 + (n % 150);
      float bias = d ? (bib2[n] + bhb2[n]) : (bif2[n] + bhf2[n]);
      float acc[32];
      #pragma unroll
      for (int si = 0; si < 32; ++si) acc[si] = bias;
      const float* wcol = W2I + (size_t)d * 300 * 608 + n;
      for (int k = 0; k < 300; ++k) {
        float wvv = wcol[(size_t)k * 608];
        #pragma unroll
        for (int si = 0; si < 32; ++si) acc[si] += wvv * se[si * 304 + k];
      }
      #pragma unroll
      for (int si = 0; si < 32; ++si)
        XG2[((size_t)d * NS + sb + si) * NG2 + n2] = acc[si];
    }
  }
  for (int e = tid; e < 32 * 40; e += 256) {
    int si = e / 40, q = e - si * 40;
    int g = q / 10, jp = 150 + (q - g * 10);
    XG2[((size_t)d * NS + sb + si) * NG2 + g * 160 + jp] = 0.f;
  }
}

// ---------------- layer-2 recurrence (round-15 proven form) ----------------
__global__ __launch_bounds__(640) void lstm2_kernel(
    const __hip_bfloat16* __restrict__ W2B, const float* __restrict__ XG2,
    float* __restrict__ H2O)
{
  const int dir = blockIdx.x;
  const int tid = threadIdx.x;
  const int lane = tid & 63;
  const int wv = tid >> 6;
  const int c16 = lane & 15;
  const int kg = lane >> 4;
  const int j = wv * 16 + c16;
  __shared__ __align__(16) __hip_bfloat16 hbuf[2][160];

  const f32x4 ZERO4 = {0.f, 0.f, 0.f, 0.f};

  const __hip_bfloat16* Wd = W2B + (size_t)dir * NP * 160;
  bf16x8 wf[5][4];
  #pragma unroll
  for (int kt = 0; kt < 5; ++kt)
    #pragma unroll
    for (int g4 = 0; g4 < 4; ++g4) {
      wf[kt][g4] = *reinterpret_cast<const bf16x8*>(
          Wd + (size_t)(g4 * 160 + j) * 160 + kt * 32 + kg * 8);
      asm volatile("" : "+v"(wf[kt][g4]));
    }

  if (tid < 160) hbuf[0][tid] = __float2bfloat16(0.f);
  __syncthreads();

  float creg = 0.f;
  const float* xg = XG2 + (size_t)dir * NS * NG2;

  float xqC[8], xqN[8];
  #pragma unroll
  for (int q = 0; q < 2; ++q)
    #pragma unroll
    for (int g4 = 0; g4 < 4; ++g4) {
      int ss2 = dir ? (1023 - q) : q;
      xqC[q * 4 + g4] = xg[(size_t)ss2 * NG2 + g4 * 160 + j];
    }

  for (int grp = 0; grp < 512; ++grp) {
    #pragma unroll
    for (int q = 0; q < 2; ++q)
      #pragma unroll
      for (int g4 = 0; g4 < 4; ++g4) {
        int sl = grp * 2 + 2 + q;
        if (sl < 1024) {
          int ss2 = dir ? (1023 - sl) : sl;
          xqN[q * 4 + g4] = xg[(size_t)ss2 * NG2 + g4 * 160 + j];
        } else {
          xqN[q * 4 + g4] = 0.f;
        }
      }
    #pragma unroll
    for (int q = 0; q < 2; ++q) {
      const int step = grp * 2 + q;
      const int ss = dir ? (1023 - step) : step;
      bf16x8 hf[5];
      #pragma unroll
      for (int kt = 0; kt < 5; ++kt)
        hf[kt] = *reinterpret_cast<const bf16x8*>(&hbuf[q][kt * 32 + kg * 8]);
      f32x4 aA[4], aB[4];
      #pragma unroll
      for (int g4 = 0; g4 < 4; ++g4) {
        aA[g4] = MFMA_B16(hf[0], wf[0][g4], ZERO4);
        aB[g4] = MFMA_B16(hf[1], wf[1][g4], ZERO4);
      }
      #pragma unroll
      for (int g4 = 0; g4 < 4; ++g4) {
        aA[g4] = MFMA_B16(hf[2], wf[2][g4], aA[g4]);
        aB[g4] = MFMA_B16(hf[3], wf[3][g4], aB[g4]);
        aA[g4] = MFMA_B16(hf[4], wf[4][g4], aA[g4]);
      }
      float iv = sigm(aA[0][0] + aB[0][0] + xqC[q * 4 + 0]);
      float fv = sigm(aA[1][0] + aB[1][0] + xqC[q * 4 + 1]);
      float gv = tanh_fast(aA[2][0] + aB[2][0] + xqC[q * 4 + 2]);
      float ov = sigm(aA[3][0] + aB[3][0] + xqC[q * 4 + 3]);
      creg = fv * creg + iv * gv;
      float nh = ov * tanh_fast(creg);
      if (kg == 0) {
        hbuf[q ^ 1][j] = __float2bfloat16(nh);
        if (j < HH) H2O[(size_t)ss * 300 + dir * HH + j] = nh;
      }
      bar_lds();
    }
    #pragma unroll
    for (int q = 0; q < 8; ++q) xqC[q] = xqN[q];
  }
}

// ---------------- head ----------------
__global__ __launch_bounds__(256, 1) void head_kernel(
    const float* __restrict__ H2O, const float* __restrict__ w_out,
    const float* __restrict__ b_out, float* __restrict__ out)
{
  int s = blockIdx.x * 256 + threadIdx.x;
  if (s >= NS) return;
  float acc[7];
  #pragma unroll
  for (int c = 0; c < 7; ++c) acc[c] = b_out[c];
  const float* hrow = H2O + (size_t)s * 300;
  for (int k = 0; k < 300; ++k) {
    float hv = hrow[k];
    #pragma unroll
    for (int c = 0; c < 7; ++c) acc[c] += hv * w_out[c * 300 + k];
  }
  float m = acc[0];
  #pragma unroll
  for (int c = 1; c < 7; ++c) m = fmaxf(m, acc[c]);
  float sum = 0.f;
  #pragma unroll
  for (int c = 0; c < 7; ++c) sum += __expf(acc[c] - m);
  float lse = m + __logf(sum);
  #pragma unroll
  for (int c = 0; c < 7; ++c) out[s * 7 + c] = acc[c] - lse;
}

extern "C" void kernel_launch(void* const* d_in, const int* in_sizes, int n_in,
                              void* d_out, int out_size, void* d_ws, size_t ws_size,
                              hipStream_t stream) {
  const float* x      = (const float*)d_in[0];
  const float* wif1   = (const float*)d_in[1];
  const float* whf1   = (const float*)d_in[2];
  const float* bif1   = (const float*)d_in[3];
  const float* bhf1   = (const float*)d_in[4];
  const float* wib1   = (const float*)d_in[5];
  const float* whb1   = (const float*)d_in[6];
  const float* bib1   = (const float*)d_in[7];
  const float* bhb1   = (const float*)d_in[8];
  const float* wif2   = (const float*)d_in[9];
  const float* whf2   = (const float*)d_in[10];
  const float* bif2   = (const float*)d_in[11];
  const float* bhf2   = (const float*)d_in[12];
  const float* wib2   = (const float*)d_in[13];
  const float* whb2   = (const float*)d_in[14];
  const float* bib2   = (const float*)d_in[15];
  const float* bhb2   = (const float*)d_in[16];
  const float* w_out  = (const float*)d_in[17];
  const float* b_out  = (const float*)d_in[18];

  char* ws = (char*)d_ws;
  __hip_bfloat16* WXp = (__hip_bfloat16*)(ws + OFF_WXP);
  __hip_bfloat16* WHp = (__hip_bfloat16*)(ws + OFF_WHP);
  float*    B1  = (float*)(ws + OFF_B1);
  __hip_bfloat16* W2B = (__hip_bfloat16*)(ws + OFF_W2B);
  float*    W2I = (float*)(ws + OFF_W2I);
  float*    SE  = (float*)(ws + OFF_SE);
  float*    XG2 = (float*)(ws + OFF_XG2);
  float*    H2O = (float*)(ws + OFF_H2O);
  __hip_bfloat16* XG1 = (__hip_bfloat16*)(ws + OFF_XG1);

  // adaptive chunk: XG1 chunk bytes = CS * 327680 (bf16 [2][CS][128][640]).
  int CS = 128;
  if (ws_size > OFF_XG1) {
    size_t avail = ws_size - OFF_XG1;
    CS = 1024;
    while (CS > 128 && (size_t)CS * 327680ull > avail) CS >>= 1;
  }

  prep_kernel<<<(PE4 + 255) / 256, 256, 0, stream>>>(
      wif1, whf1, bif1, bhf1, wib1, whb1, bib1, bhb1,
      wif2, wib2, whf2, whb2, WXp, WHp, B1, W2B, W2I);

  (void)hipFuncSetAttribute((const void*)xg1_gemm,
                            hipFuncAttributeMaxDynamicSharedMemorySize, GA_SMEM);
  for (int sBase = 0; sBase < NS; sBase += CS) {
    xg1_gemm<<<CS, 512, GA_SMEM, stream>>>(x, WXp, B1, XG1, sBase, CS);
    lstm1_rec<<<CS / 4, 640, 0, stream>>>(XG1, WHp, SE, sBase, CS);
  }

  xg2_kernel<<<64, 256, 0, stream>>>(SE, W2I, bif2, bhf2, bib2, bhb2, XG2);

  lstm2_kernel<<<2, 640, 0, stream>>>(W2B, XG2, H2O);

  head_kernel<<<4, 256, 0, stream>>>(H2O, w_out, b_out, (float*)d_out);
}